// Round 2
// baseline (1080.630 us; speedup 1.0000x reference)
//
#include <hip/hip_runtime.h>
#include <stdint.h>

#define FP8_MAX 448.0f
#define TOKENS  8192
#define IDIM    4096
#define ODIM    4096

typedef float f32x4 __attribute__((ext_vector_type(4)));
typedef int   i32x4 __attribute__((ext_vector_type(4)));
typedef int   i32x8 __attribute__((ext_vector_type(8)));

__device__ __forceinline__ void async_copy16(const uint8_t* g, uint8_t* l) {
  __builtin_amdgcn_global_load_lds((const __attribute__((address_space(1))) void*)g,
                                   (__attribute__((address_space(3))) void*)l,
                                   16, 0, 0);
}

__device__ __forceinline__ i32x8 ldfrag(const uint8_t* p, int o0, int o1) {
  i32x4 lo = *(const i32x4*)(p + o0);
  i32x4 hi = *(const i32x4*)(p + o1);
  return __builtin_shufflevector(lo, hi, 0, 1, 2, 3, 4, 5, 6, 7);
}

// ---------------- fused prep, wave-per-row ----------------
// blocks 0..2047: x-rows (4 rows/block, 1 row/wave) -> per-token quant
// blocks 2048..3071: w-rows (4 rows/block) -> f32->fp8 convert (exact: w is fp8-valued)
__global__ __launch_bounds__(256) void prep_kernel(
    const float* __restrict__ x, const float* __restrict__ w,
    uint8_t* __restrict__ xq, uint8_t* __restrict__ wq, float* __restrict__ xsc) {
  const int lane = threadIdx.x & 63;
  const int wid  = threadIdx.x >> 6;

  if (blockIdx.x < 2048) {
    const int row = blockIdx.x * 4 + wid;
    const f32x4* xr = (const f32x4*)(x + (size_t)row * IDIM);

    f32x4 v[16];
    float amax = 0.0f;
    #pragma unroll
    for (int k = 0; k < 16; k++) {
      v[k] = xr[lane + k * 64];
      amax = fmaxf(amax, fmaxf(fmaxf(fabsf(v[k].x), fabsf(v[k].y)),
                               fmaxf(fabsf(v[k].z), fabsf(v[k].w))));
    }
    #pragma unroll
    for (int off = 32; off > 0; off >>= 1)
      amax = fmaxf(amax, __shfl_xor(amax, off, 64));
    amax = fmaxf(amax, 1e-12f);
    const float scale = amax / FP8_MAX;     // matches ref: amax/448 in f32
    if (lane == 0) xsc[row] = scale;

    uint32_t* out = (uint32_t*)(xq + (size_t)row * IDIM);
    #pragma unroll
    for (int k = 0; k < 16; k++) {
      // exact f32 divide to match reference rounding, then RNE fp8 cast
      float a = v[k].x / scale, b = v[k].y / scale;
      float c = v[k].z / scale, d = v[k].w / scale;
      int p = __builtin_amdgcn_cvt_pk_fp8_f32(a, b, 0, false);
      p = __builtin_amdgcn_cvt_pk_fp8_f32(c, d, p, true);
      out[lane + k * 64] = (uint32_t)p;
    }
  } else {
    const int row = (blockIdx.x - 2048) * 4 + wid;
    const f32x4* wp = (const f32x4*)(w + (size_t)row * IDIM);
    uint32_t* out = (uint32_t*)(wq + (size_t)row * IDIM);
    #pragma unroll
    for (int k = 0; k < 16; k++) {
      f32x4 t = wp[lane + k * 64];
      int p = __builtin_amdgcn_cvt_pk_fp8_f32(t.x, t.y, 0, false);
      p = __builtin_amdgcn_cvt_pk_fp8_f32(t.z, t.w, p, true);
      out[lane + k * 64] = (uint32_t)p;
    }
  }
}

// ---------------- fp8 block-scaled GEMM: 256x256 tile, 2-phase/K-tile raw-barrier pipeline ----------------
// y[t][o] = x_scale[t] * sum_kb wsi[o/128][kb] * sum_{k in kb} xq[t][k]*wq[o][k]
// 512 thr = 8 waves (2M x 4N), per-wave 128x64 output (8x4 16x16 frags), BK=128.
// Per K-tile: phase0 {ds_read A0-3,B0-3 | issue 8 gload_lds for next tile | s_barrier |
//             setprio1 | 16 MFMA | setprio0 | s_barrier}
//             phase1 {ds_read A4-7 (B held in regs) | s_barrier | 16 MFMA |
//             vmcnt(0) (only next-tile loads outstanding, issued a full phase ago) | s_barrier}.
// Raw s_barrier (no vmcnt drain) keeps prefetch loads in flight across phases -> breaks
// the __syncthreads-drain ceiling that capped rounds 0/1.
__global__ __launch_bounds__(512, 2) void gemm_fp8_kernel(
    const uint8_t* __restrict__ xq, const uint8_t* __restrict__ wq,
    const float* __restrict__ xsc, const float* __restrict__ wsi,
    float* __restrict__ y) {
  __shared__ __align__(16) uint8_t As0[32768];
  __shared__ __align__(16) uint8_t Bs0[32768];
  __shared__ __align__(16) uint8_t As1[32768];
  __shared__ __align__(16) uint8_t Bs1[32768];

  const int tid  = threadIdx.x;
  const int bo   = blockIdx.x & 15;   // 16 o-tiles
  const int bt   = blockIdx.x >> 4;   // 32 t-tiles
  const int t0   = bt << 8;
  const int o0   = bo << 8;
  const int lane = tid & 63;
  const int wv   = tid >> 6;
  const int wr   = (wv >> 2) << 7;    // 0 / 128 : wave token offset
  const int wc   = (wv & 3) << 6;     // 0/64/128/192 : wave output offset
  const int ln   = lane & 15;
  const int quad = lane >> 4;

  // Staging: 8 x 16B/thread per K-tile. Slot s = u*512+tid -> (row=s>>3, slot=s&7);
  // global src chunk = slot ^ (row&7) (XOR swizzle lives in src addr; LDS dst linear).
  const int rb  = tid >> 3;                       // row within 64-row group (u*64 + rb)
  const int cs  = ((tid & 7) ^ (rb & 7)) << 4;    // swizzled byte offset in row
  const int dst = tid << 4;

  // MFMA A/B operand (16x16x128): row = lane&15, k bytes = quad*32..+32
  // -> chunks c0, c0+1 of row, XOR-unswizzled.
  const int c0   = quad << 1;
  const int sw   = ln & 7;
  const int sw0  = ((c0    ) ^ sw) << 4;
  const int sw1  = ((c0 + 1) ^ sw) << 4;
  const int ab   = (wr + ln) * 128;   // A byte base (row stride 128B)
  const int bb   = (wc + ln) * 128;   // B byte base

  f32x4 outer[8][4];
  #pragma unroll
  for (int i = 0; i < 8; i++)
    #pragma unroll
    for (int j = 0; j < 4; j++)
      outer[i][j] = (f32x4)(0.0f);

  // weight scale row: o-tile spans two 128-blocks; wave's 64-col slice sits in one.
  const float* wsrow = wsi + (bo * 2 + (wc >> 7)) * 32;
  const int ident = 0x7f7f7f7f;       // e8m0 identity scale
  const f32x4 zero4 = (f32x4)(0.0f);

  auto stageA = [&](uint8_t* Aw, int k0) {
    #pragma unroll
    for (int u = 0; u < 4; u++)
      async_copy16(xq + ((size_t)(t0 + u * 64 + rb) << 12) + (k0 + cs),
                   Aw + u * 8192 + dst);
  };
  auto stageB = [&](uint8_t* Bw, int k0) {
    #pragma unroll
    for (int u = 0; u < 4; u++)
      async_copy16(wq + ((size_t)(o0 + u * 64 + rb) << 12) + (k0 + cs),
                   Bw + u * 8192 + dst);
  };

  auto tile = [&](const uint8_t* Ar, const uint8_t* Br, uint8_t* Aw, uint8_t* Bw,
                  int kb, bool doStage) {
    const float s = wsrow[kb];
    const int kn = (kb + 1) << 7;
    i32x8 a[4], b[4];

    // ---- phase 0: frags + next-tile prefetch ----
    #pragma unroll
    for (int i = 0; i < 4; i++)
      a[i] = ldfrag(Ar + ab + i * 2048, sw0, sw1);
    #pragma unroll
    for (int j = 0; j < 4; j++)
      b[j] = ldfrag(Br + bb + j * 2048, sw0, sw1);
    if (doStage) { stageA(Aw, kn); stageB(Bw, kn); }
    __builtin_amdgcn_s_barrier();
    __builtin_amdgcn_sched_barrier(0);
    __builtin_amdgcn_s_setprio(1);
    #pragma unroll
    for (int i = 0; i < 4; i++)
      #pragma unroll
      for (int j = 0; j < 4; j++) {
        f32x4 t = __builtin_amdgcn_mfma_scale_f32_16x16x128_f8f6f4(
            a[i], b[j], zero4, 0, 0, 0, ident, 0, ident);
        outer[i][j] += s * t;
      }
    __builtin_amdgcn_s_setprio(0);
    __builtin_amdgcn_s_barrier();
    __builtin_amdgcn_sched_barrier(0);

    // ---- phase 1: upper A half, B held in regs ----
    #pragma unroll
    for (int i = 0; i < 4; i++)
      a[i] = ldfrag(Ar + ab + 8192 + i * 2048, sw0, sw1);
    __builtin_amdgcn_s_barrier();
    __builtin_amdgcn_sched_barrier(0);
    __builtin_amdgcn_s_setprio(1);
    #pragma unroll
    for (int i = 0; i < 4; i++)
      #pragma unroll
      for (int j = 0; j < 4; j++) {
        f32x4 t = __builtin_amdgcn_mfma_scale_f32_16x16x128_f8f6f4(
            a[i], b[j], zero4, 0, 0, 0, ident, 0, ident);
        outer[i + 4][j] += s * t;
      }
    __builtin_amdgcn_s_setprio(0);
    // tile boundary: wait own next-tile loads (issued a full phase ago), then barrier
    asm volatile("s_waitcnt vmcnt(0)" ::: "memory");
    __builtin_amdgcn_s_barrier();
    __builtin_amdgcn_sched_barrier(0);
  };

  // prologue: stage tile 0
  stageA(As0, 0); stageB(Bs0, 0);
  asm volatile("s_waitcnt vmcnt(0)" ::: "memory");
  __builtin_amdgcn_s_barrier();
  __builtin_amdgcn_sched_barrier(0);

  #pragma unroll 1
  for (int kb = 0; kb < 32; kb += 2) {
    tile(As0, Bs0, As1, Bs1, kb, true);
    tile(As1, Bs1, As0, Bs0, kb + 1, kb + 1 < 31);
  }

  // epilogue: C/D frag (row = quad*4+reg -> token, col = ln -> output), * x_scale[t]
  #pragma unroll
  for (int i = 0; i < 8; i++) {
    #pragma unroll
    for (int r = 0; r < 4; r++) {
      const int t = t0 + wr + i * 16 + quad * 4 + r;
      const float sc = xsc[t];
      float* yp = y + ((size_t)t << 12) + o0 + wc + ln;
      #pragma unroll
      for (int j = 0; j < 4; j++)
        yp[j * 16] = outer[i][j][r] * sc;
    }
  }
}

extern "C" void kernel_launch(void* const* d_in, const int* in_sizes, int n_in,
                              void* d_out, int out_size, void* d_ws, size_t ws_size,
                              hipStream_t stream) {
  const float* x   = (const float*)d_in[0];   // [8192,4096] f32
  const float* w   = (const float*)d_in[1];   // [4096,4096] f32 (fp8-valued)
  const float* wsi = (const float*)d_in[2];   // [32,32] f32
  float* y = (float*)d_out;                   // [8192,4096] f32

  // workspace layout: 33.55MB xq + 16.78MB wq + 32KB xsc
  uint8_t* xq = (uint8_t*)d_ws;
  uint8_t* wq = xq + (size_t)TOKENS * IDIM;
  float*  xsc = (float*)(wq + (size_t)ODIM * IDIM);

  prep_kernel<<<3072, 256, 0, stream>>>(x, w, xq, wq, xsc);
  gemm_fp8_kernel<<<(TOKENS / 256) * (ODIM / 256), 512, 0, stream>>>(xq, wq, xsc, wsi, y);
}

// Round 3
// 437.957 us; speedup vs baseline: 2.4674x; 2.4674x over previous
//
#include <hip/hip_runtime.h>
#include <stdint.h>

#define FP8_MAX 448.0f
#define TOKENS  8192
#define IDIM    4096
#define ODIM    4096

typedef float f32x4 __attribute__((ext_vector_type(4)));
typedef int   i32x4 __attribute__((ext_vector_type(4)));
typedef int   i32x8 __attribute__((ext_vector_type(8)));

__device__ __forceinline__ void async_copy16(const uint8_t* g, uint8_t* l) {
  __builtin_amdgcn_global_load_lds((const __attribute__((address_space(1))) void*)g,
                                   (__attribute__((address_space(3))) void*)l,
                                   16, 0, 0);
}

// ---------------- fused prep, wave-per-row: no barriers, no LDS ----------------
// blocks 0..2047: x-rows (4 rows/block, 1 row/wave) -> per-token quant
// blocks 2048..3071: w-rows (4 rows/block) -> f32->fp8 convert (exact: w is fp8-valued)
__global__ __launch_bounds__(256) void prep_kernel(
    const float* __restrict__ x, const float* __restrict__ w,
    uint8_t* __restrict__ xq, uint8_t* __restrict__ wq, float* __restrict__ xsc) {
  const int lane = threadIdx.x & 63;
  const int wid  = threadIdx.x >> 6;

  if (blockIdx.x < 2048) {
    const int row = blockIdx.x * 4 + wid;
    const f32x4* xr = (const f32x4*)(x + (size_t)row * IDIM);

    f32x4 v[16];
    float amax = 0.0f;
    #pragma unroll
    for (int k = 0; k < 16; k++) {
      v[k] = xr[lane + k * 64];                           // coalesced 16B/lane
      amax = fmaxf(amax, fmaxf(fmaxf(fabsf(v[k].x), fabsf(v[k].y)),
                               fmaxf(fabsf(v[k].z), fabsf(v[k].w))));
    }
    #pragma unroll
    for (int off = 32; off > 0; off >>= 1)
      amax = fmaxf(amax, __shfl_xor(amax, off, 64));
    amax = fmaxf(amax, 1e-12f);
    const float scale = amax / FP8_MAX;                   // matches ref: amax/448 in f32
    if (lane == 0) xsc[row] = scale;

    uint32_t* out = (uint32_t*)(xq + (size_t)row * IDIM);
    #pragma unroll
    for (int k = 0; k < 16; k++) {
      // exact f32 divide to match reference rounding, then RNE fp8 cast
      float a = v[k].x / scale, b = v[k].y / scale;
      float c = v[k].z / scale, d = v[k].w / scale;
      int p = __builtin_amdgcn_cvt_pk_fp8_f32(a, b, 0, false);
      p = __builtin_amdgcn_cvt_pk_fp8_f32(c, d, p, true);
      out[lane + k * 64] = (uint32_t)p;
    }
  } else {
    const int row = (blockIdx.x - 2048) * 4 + wid;
    const f32x4* wp = (const f32x4*)(w + (size_t)row * IDIM);
    uint32_t* out = (uint32_t*)(wq + (size_t)row * IDIM);
    #pragma unroll
    for (int k = 0; k < 16; k++) {
      f32x4 t = wp[lane + k * 64];
      int p = __builtin_amdgcn_cvt_pk_fp8_f32(t.x, t.y, 0, false);
      p = __builtin_amdgcn_cvt_pk_fp8_f32(t.z, t.w, p, true);
      out[lane + k * 64] = (uint32_t)p;
    }
  }
}

// ---------------- fp8 block-scaled GEMM, double-buffered prefetch pipeline ----------------
// y[t][o] = x_scale[t] * sum_kb wsi[o/128][kb] * sum_{k in kb} xq[t][k]*wq[o][k]
// 128x128 tile per block (4 waves, each 64x64 via 4x4 16x16 frags), BK=128.
// Pipeline: STAGE(kb+1) issued BEFORE compute(kb); single __syncthreads per kb.
// vs round 1: XCD swizzle REMOVED (FETCH 157->400MB showed it destroyed L2 locality;
// data is L3-resident so it had no upside). Default block order = round-0's (bo fastest:
// consecutive blocks share the A-panel).
__global__ __launch_bounds__(256) void gemm_fp8_kernel(
    const uint8_t* __restrict__ xq, const uint8_t* __restrict__ wq,
    const float* __restrict__ xsc, const float* __restrict__ wsi,
    float* __restrict__ y) {
  __shared__ __align__(16) uint8_t As0[128 * 128];
  __shared__ __align__(16) uint8_t Bs0[128 * 128];
  __shared__ __align__(16) uint8_t As1[128 * 128];
  __shared__ __align__(16) uint8_t Bs1[128 * 128];

  const int tid  = threadIdx.x;
  const int bo   = blockIdx.x & 31;   // 32 o-tiles (fastest: neighbors share A-panel)
  const int bt   = blockIdx.x >> 5;   // 64 t-tiles
  const int t0   = bt << 7;
  const int o0   = bo << 7;
  const int lane = tid & 63;
  const int wave = tid >> 6;
  const int wr   = (wave >> 1) << 6;  // wave token offset in tile
  const int wc   = (wave & 1) << 6;   // wave output offset in tile
  const int ln   = lane & 15;
  const int quad = lane >> 4;

  // Staging: LDS 16B-slot j holds global (row=j>>3, chunk=(j&7)^(row&7)).
  // Swizzle lives in the global source address; LDS dst stays lane-contiguous
  // (global_load_lds requires wave-uniform base + lane*16 dst).
  const int rb  = tid >> 3;                          // row within 32-row group
  const int cs  = ((tid & 7) ^ (rb & 7)) << 4;       // swizzled byte offset in row
  const int lds = tid << 4;

  // A-operand layout for 16x16x128 f8f6f4: row = lane&15, k = quad*32 + byte(0..31)
  const int c0 = quad << 1;
  int aoff[4][2], boff[4][2];
  #pragma unroll
  for (int i = 0; i < 4; i++) {
    const int ra = wr + i * 16 + ln;
    const int sa = ra & 7;
    aoff[i][0] = ra * 128 + ((c0 ^ sa) << 4);
    aoff[i][1] = ra * 128 + (((c0 + 1) ^ sa) << 4);
    const int rb2 = wc + i * 16 + ln;
    const int sb = rb2 & 7;
    boff[i][0] = rb2 * 128 + ((c0 ^ sb) << 4);
    boff[i][1] = rb2 * 128 + (((c0 + 1) ^ sb) << 4);
  }

  f32x4 outer[4][4];
  #pragma unroll
  for (int i = 0; i < 4; i++)
    #pragma unroll
    for (int j = 0; j < 4; j++)
      outer[i][j] = (f32x4)(0.0f);

  const float* wsrow = wsi + bo * 32;     // weight_scale_inv[bo][*]
  const int ident = 0x7f7f7f7f;           // e8m0 identity scale (2^0) in all bytes
  const f32x4 zero4 = (f32x4)(0.0f);

  auto stage = [&](uint8_t* Ad, uint8_t* Bd, int kb) {
    const int k0 = kb << 7;
    #pragma unroll
    for (int u = 0; u < 4; u++) {
      async_copy16(xq + ((size_t)(t0 + u * 32 + rb) << 12) + (k0 + cs),
                   Ad + u * 4096 + lds);
      async_copy16(wq + ((size_t)(o0 + u * 32 + rb) << 12) + (k0 + cs),
                   Bd + u * 4096 + lds);
    }
  };

  auto compute = [&](const uint8_t* Ab, const uint8_t* Bb, float s) {
    i32x8 a[4], b[4];
    #pragma unroll
    for (int i = 0; i < 4; i++) {
      i32x4 alo = *(const i32x4*)(Ab + aoff[i][0]);
      i32x4 ahi = *(const i32x4*)(Ab + aoff[i][1]);
      a[i] = __builtin_shufflevector(alo, ahi, 0, 1, 2, 3, 4, 5, 6, 7);
      i32x4 blo = *(const i32x4*)(Bb + boff[i][0]);
      i32x4 bhi = *(const i32x4*)(Bb + boff[i][1]);
      b[i] = __builtin_shufflevector(blo, bhi, 0, 1, 2, 3, 4, 5, 6, 7);
    }
    #pragma unroll
    for (int i = 0; i < 4; i++)
      #pragma unroll
      for (int j = 0; j < 4; j++) {
        f32x4 t = __builtin_amdgcn_mfma_scale_f32_16x16x128_f8f6f4(
            a[i], b[j], zero4, 0, 0, 0, ident, 0, ident);
        outer[i][j] += s * t;
      }
  };

  // prologue
  stage(As0, Bs0, 0);
  __syncthreads();

  // main loop, manually 2x-unrolled so the buffer select is compile-time
  for (int kb = 0; kb < 32; kb += 2) {
    if (kb + 1 < 32) stage(As1, Bs1, kb + 1);   // prefetch issues first
    compute(As0, Bs0, wsrow[kb]);               // hide prefetch under MFMA
    __syncthreads();                            // vmcnt+lgkm drain + barrier

    if (kb + 2 < 32) stage(As0, Bs0, kb + 2);
    compute(As1, Bs1, wsrow[kb + 1]);
    __syncthreads();
  }

  // epilogue: C/D frag (row = quad*4+reg -> token, col = ln -> output), * x_scale[t]
  #pragma unroll
  for (int i = 0; i < 4; i++) {
    #pragma unroll
    for (int r = 0; r < 4; r++) {
      const int t = t0 + wr + i * 16 + quad * 4 + r;
      const float sc = xsc[t];
      float* yp = y + ((size_t)t << 12) + o0 + wc + ln;
      #pragma unroll
      for (int j = 0; j < 4; j++)
        yp[j * 16] = outer[i][j][r] * sc;
    }
  }
}

extern "C" void kernel_launch(void* const* d_in, const int* in_sizes, int n_in,
                              void* d_out, int out_size, void* d_ws, size_t ws_size,
                              hipStream_t stream) {
  const float* x   = (const float*)d_in[0];   // [8192,4096] f32
  const float* w   = (const float*)d_in[1];   // [4096,4096] f32 (fp8-valued)
  const float* wsi = (const float*)d_in[2];   // [32,32] f32
  float* y = (float*)d_out;                   // [8192,4096] f32

  // workspace layout: 33.55MB xq + 16.78MB wq + 32KB xsc
  uint8_t* xq = (uint8_t*)d_ws;
  uint8_t* wq = xq + (size_t)TOKENS * IDIM;
  float*  xsc = (float*)(wq + (size_t)ODIM * IDIM);

  prep_kernel<<<3072, 256, 0, stream>>>(x, w, xq, wq, xsc);
  gemm_fp8_kernel<<<2048, 256, 0, stream>>>(xq, wq, xsc, wsi, y);
}